// Round 4
// baseline (320.422 us; speedup 1.0000x reference)
//
#include <hip/hip_runtime.h>

typedef __bf16 bf16;
typedef __attribute__((ext_vector_type(8))) __bf16 bf16x8;
typedef __attribute__((ext_vector_type(4))) __bf16 bf16x4;
typedef __attribute__((ext_vector_type(4))) float f32x4;
typedef __attribute__((ext_vector_type(4))) short short4v;

// ---- constants for this problem ----
#define BB 2
#define TT 2048
#define DD 2048
#define HH 16
#define HKV 4
#define DHD 128
#define NQKV 3072   // H*DH + 2*HKV*DH

__device__ __forceinline__ void gl_lds16(const bf16* g, bf16* l) {
    __builtin_amdgcn_global_load_lds(
        (const __attribute__((address_space(1))) void*)g,
        (__attribute__((address_space(3))) void*)l, 16, 0, 0);
}

// ---------------- fp32 -> bf16 convert ----------------
__global__ void cvt_bf16(const float* __restrict__ src, bf16* __restrict__ dst, int n8) {
    int i = blockIdx.x * 256 + threadIdx.x;
    if (i >= n8) return;
    float4 a = ((const float4*)src)[i * 2];
    float4 b = ((const float4*)src)[i * 2 + 1];
    bf16x8 v;
    v[0] = (bf16)a.x; v[1] = (bf16)a.y; v[2] = (bf16)a.z; v[3] = (bf16)a.w;
    v[4] = (bf16)b.x; v[5] = (bf16)b.y; v[6] = (bf16)b.z; v[7] = (bf16)b.w;
    *(bf16x8*)(dst + (size_t)i * 8) = v;
}

// ---------------- GEMM: C = A(MxK) * Bw(NxK)^T ----------------
// R9: R8's phased schedule with the cross-wave race FIXED:
//   phase = { s_waitcnt vmcnt(6); s_barrier; [compiler fence];
//             8x ds_read_b128; stage (3x global_load_lds);
//             setprio(1); 16 MFMA; setprio(0) }
// vmcnt->barrier ordering guarantees ALL waves' loads for this phase's
// buffer half landed before any wave ds_reads it (vmcnt is per-wave; the
// barrier propagates the drain). Single barrier/phase also covers the WAR
// hazard: the half staged at P was last read at P-1, and those reads are
// lgkm-drained (compiler wait before MFMA) before each wave reaches
// barrier(P). Empty asm memory fence after the barrier stops the compiler
// hoisting ds_read/stage above the raw s_barrier.
// Tile BM=128 x BN=256, BK=64 halves, 512 thr (8 waves, 2M x 4N, 64x64 per
// wave). LDS 96 KiB, linear dest for global_load_lds; logical K-chunk XOR'd
// into the GLOBAL source (c = (lane&3)^((lane>>3)&3)); frag reads apply
// quad^((l15>>1)&3). Conflict-free per 8-lane b128 phase.
// MODE 0: fp32 store. MODE 1: fused QKV epilogue, 2 heads per block.
template <int MODE>
__global__ __launch_bounds__(512, 2)
void gemm_bt(const bf16* __restrict__ A, const bf16* __restrict__ Bw,
             int M, int N, int K,
             float* __restrict__ Cout,
             bf16* __restrict__ qb, bf16* __restrict__ kb,
             bf16* __restrict__ vtb,
             const float* __restrict__ v1,
             const float* __restrict__ cosb,
             const float* __restrict__ sinb,
             const float* __restrict__ lamp) {
    __shared__ bf16 smem[49152];          // 96 KiB
    bf16* As = smem;                      // 16384 ele
    bf16* Bs = smem + 16384;              // 32768 ele
    const int tid = threadIdx.x;
    const int w = tid >> 6, lane = tid & 63;
    const int l15 = lane & 15, quad = lane >> 4;
    const int wr = w >> 2, wc = w & 3;    // wave row (2) / col (4)
    const int m0 = blockIdx.y * 128, n0 = blockIdx.x * 256;

    // staging constants: lane -> (row sr, pre-swizzled k-chunk sc)
    const int sr = lane >> 2;
    const int sc = ((lane & 3) ^ ((lane >> 3) & 3)) * 8;
    const int tmax = (K >> 6) - 1;

    f32x4 acc[4][4] = {};

    auto stage = [&](int t, int kh) {
        int tc = t > tmax ? tmax : t;
        int buf = t & 1;
        size_t kk = (size_t)(tc << 6) + (kh << 5) + sc;
        gl_lds16(A + (size_t)(m0 + w * 16 + sr) * K + kk,
                 As + buf * 8192 + kh * 4096 + w * 512);
        gl_lds16(Bw + (size_t)(n0 + w * 16 + sr) * K + kk,
                 Bs + buf * 16384 + kh * 8192 + w * 512);
        gl_lds16(Bw + (size_t)(n0 + 128 + w * 16 + sr) * K + kk,
                 Bs + buf * 16384 + kh * 8192 + 4096 + w * 512);
    };

    const int xs = (quad ^ ((l15 >> 1) & 3)) * 8;   // read-side swizzle

    auto phase = [&](int buf, int kh, int st, int skh) {
        asm volatile("s_waitcnt vmcnt(6)" ::: "memory");
        __builtin_amdgcn_s_barrier();
        asm volatile("" ::: "memory");      // no hoist of reads/stage above barrier
        bf16x8 af[4], bfr[4];
        const bf16* Ab = As + buf * 8192 + kh * 4096;
        const bf16* Bb = Bs + buf * 16384 + kh * 8192;
#pragma unroll
        for (int mi = 0; mi < 4; mi++)
            af[mi] = *(const bf16x8*)(Ab + (wr * 64 + mi * 16 + l15) * 32 + xs);
#pragma unroll
        for (int ni = 0; ni < 4; ni++)
            bfr[ni] = *(const bf16x8*)(Bb + (wc * 64 + ni * 16 + l15) * 32 + xs);
        stage(st, skh);
        __builtin_amdgcn_s_setprio(1);
#pragma unroll
        for (int mi = 0; mi < 4; mi++)
#pragma unroll
            for (int ni = 0; ni < 4; ni++)
                acc[mi][ni] = __builtin_amdgcn_mfma_f32_16x16x32_bf16(af[mi], bfr[ni], acc[mi][ni], 0, 0, 0);
        __builtin_amdgcn_s_setprio(0);
    };

    // prologue: t0.k0, t0.k1, t1.k0 (9 loads outstanding)
    stage(0, 0); stage(0, 1); stage(1, 0);
    const int nit = K >> 7;
    for (int i = 0; i < nit; i++) {
        int t2 = 2 * i;
        phase(0, 0, t2 + 1, 1);    // compute tile 2i   kh0; stage (2i+1).k1
        phase(0, 1, t2 + 2, 0);    // compute tile 2i   kh1; stage (2i+2).k0
        phase(1, 0, t2 + 2, 1);    // compute tile 2i+1 kh0; stage (2i+2).k1
        phase(1, 1, t2 + 3, 0);    // compute tile 2i+1 kh1; stage (2i+3).k0
    }
    __syncthreads();   // drains tail garbage stages (vmcnt 0); epilogue reuses LDS

    if constexpr (MODE == 0) {
#pragma unroll
        for (int mi = 0; mi < 4; mi++)
#pragma unroll
            for (int ni = 0; ni < 4; ni++)
#pragma unroll
                for (int r = 0; r < 4; r++) {
                    int m = m0 + wr * 64 + mi * 16 + quad * 4 + r;
                    int n = n0 + wc * 64 + ni * 16 + l15;
                    Cout[(size_t)m * N + n] = acc[mi][ni][r];
                }
    } else {
        const int hp = n0 >> 7;           // even head base (0..22)
        const int b = m0 >> 11;
        const int t0 = m0 & (TT - 1);
        bf16* ep = smem;                  // [2 heads][128][136]

        if (hp < 20) {
            // ---- rmsnorm partials: per row, per wave-col slice ----
            float* ssum = (float*)(smem + 34816);   // [4 wc][128 rows]
            float ssq[4][4];
#pragma unroll
            for (int mi = 0; mi < 4; mi++)
#pragma unroll
                for (int r = 0; r < 4; r++) {
                    float s = 0.f;
#pragma unroll
                    for (int ni = 0; ni < 4; ni++) {
                        float v = acc[mi][ni][r];
                        s += v * v;
                    }
                    s += __shfl_xor(s, 1);
                    s += __shfl_xor(s, 2);
                    s += __shfl_xor(s, 4);
                    s += __shfl_xor(s, 8);
                    ssq[mi][r] = s;
                }
            if (l15 == 0) {
#pragma unroll
                for (int mi = 0; mi < 4; mi++)
#pragma unroll
                    for (int r = 0; r < 4; r++)
                        ssum[wc * 128 + wr * 64 + mi * 16 + quad * 4 + r] = ssq[mi][r];
            }
            __syncthreads();
            const float QSCALE = 0.08838834764831845f * 1.4426950408889634f;
            float rn[4][4];
#pragma unroll
            for (int mi = 0; mi < 4; mi++)
#pragma unroll
                for (int r = 0; r < 4; r++) {
                    int row = wr * 64 + mi * 16 + quad * 4 + r;
                    float ss = ssum[(wc & ~1) * 128 + row] + ssum[((wc & ~1) + 1) * 128 + row];
                    float rv = rsqrtf(ss * (1.f / 128.f) + 1e-6f);
                    if (hp < HH) rv *= QSCALE;
                    rn[mi][r] = rv;
                }
            // ---- rope -> ep[head][t_local][outcol] ----
#pragma unroll
            for (int mi = 0; mi < 4; mi++)
#pragma unroll
                for (int ni = 0; ni < 4; ni++)
#pragma unroll
                    for (int r = 0; r < 4; r++) {
                        float sv = acc[mi][ni][r] * rn[mi][r];
                        float pv = __shfl_xor(sv, 1);
                        int nl = (wc & 1) * 64 + ni * 16 + l15;   // 0..127 in head
                        int j = nl >> 1;
                        int tl = wr * 64 + mi * 16 + quad * 4 + r;
                        float c = cosb[(size_t)(t0 + tl) * 64 + j];
                        float s = sinb[(size_t)(t0 + tl) * 64 + j];
                        float o = (nl & 1) ? (sv * c + pv * s) : (sv * c - pv * s);
                        int oc = (nl & 1) ? (64 + j) : j;
                        ep[(wc >> 1) * 17408 + tl * 136 + oc] = (bf16)o;
                    }
            __syncthreads();
            int tl = tid >> 2, sg = tid & 3;
#pragma unroll
            for (int hd = 0; hd < 2; hd++) {
                int hg = hp + hd;
                bf16* dst = (hp < HH)
                    ? (qb + ((size_t)(b * HH + hg) * TT + t0) * DHD)
                    : (kb + ((size_t)(b * HKV + (hg - HH)) * TT + t0) * DHD);
#pragma unroll
                for (int c8 = 0; c8 < 4; c8++)
                    *(bf16x8*)(dst + (size_t)tl * DHD + sg * 8 + c8 * 32) =
                        *(const bf16x8*)(ep + hd * 17408 + tl * 136 + sg * 8 + c8 * 32);
            }
        } else {
            // ---- v: mix with v1, transpose -> vtb (B,HKV,DH,T) ----
            float lam = lamp[0];
#pragma unroll
            for (int mi = 0; mi < 4; mi++)
#pragma unroll
                for (int ni = 0; ni < 4; ni++)
#pragma unroll
                    for (int r = 0; r < 4; r++) {
                        int d = (wc & 1) * 64 + ni * 16 + l15;
                        int tl = wr * 64 + mi * 16 + quad * 4 + r;
                        int vh = hp + (wc >> 1) - 20;
                        float val = acc[mi][ni][r];
                        float vm = val + lam * (v1[((size_t)(b * HKV + vh) * TT + t0 + tl) * DHD + d] - val);
                        ep[(wc >> 1) * 17408 + d * 136 + tl] = (bf16)vm;
                    }
            __syncthreads();
            int dd = tid >> 2, sg = tid & 3;
#pragma unroll
            for (int hd = 0; hd < 2; hd++) {
                int vh = hp + hd - 20;
                bf16* dstv = vtb + ((size_t)(b * HKV + vh) * DHD) * TT + t0;
#pragma unroll
                for (int c8 = 0; c8 < 4; c8++)
                    *(bf16x8*)(dstv + (size_t)dd * TT + sg * 8 + c8 * 32) =
                        *(const bf16x8*)(ep + hd * 17408 + dd * 136 + sg * 8 + c8 * 32);
            }
        }
    }
}

// ---------------- gates = sigmoid(x[:, :16] @ gate_w^T) ----------------
__global__ void gatesk(const float* __restrict__ x, const float* __restrict__ gw,
                       float* __restrict__ gates) {
    __shared__ float gws[256];
    gws[threadIdx.x] = gw[threadIdx.x];
    __syncthreads();
    int idx = blockIdx.x * 256 + threadIdx.x;
    int h = idx & 15, token = idx >> 4;
    const float* xr = x + (size_t)token * DD;
    float z = 0.f;
#pragma unroll
    for (int j = 0; j < 16; j++) z += xr[j] * gws[h * 16 + j];
    gates[idx] = 1.f / (1.f + __expf(-z));
}

// ---------------- flash attention (unchanged from R7) ----------------
__global__ __launch_bounds__(512, 2) void fattn(const bf16* __restrict__ qbuf,
                                                const bf16* __restrict__ kbuf,
                                                const bf16* __restrict__ vt,
                                                const float* __restrict__ gates,
                                                bf16* __restrict__ yb) {
    __shared__ bf16 Ks[2][4 * 2048];
    __shared__ bf16 VTs[2][8192];     // [128 d][64 k], slot16 ^= (d&7)

    const int bid = blockIdx.x;          // 256 blocks
    const int bh = bid & 31;             // b*16+h
    const int g = bid >> 5;              // 0..7
    const int h = bh & 15, b = bh >> 4;
    const int hk = h >> 2;
    const int tid = threadIdx.x, w = tid >> 6, lane = tid & 63;
    const int wq = w & 3, grp = w >> 2;
    const int l15 = lane & 15, quad = lane >> 4;

    const bf16* qbase = qbuf + ((size_t)(b * HH + h) * TT) * DHD;
    const bf16* kbase = kbuf + ((size_t)(b * HKV + hk) * TT) * DHD;
    const bf16* vtbase = vt + ((size_t)(b * HKV + hk) * DHD) * TT;

    const int Tq0 = grp ? (15 - g) : g;
    const int Tq1 = grp ? (16 + g) : (31 - g);
    const int ktmax_blk = 31 - g;

    bf16x8 qf0[4], qf1[4];
#pragma unroll
    for (int kc = 0; kc < 4; kc++) {
        qf0[kc] = *(const bf16x8*)(qbase + (size_t)(Tq0 * 64 + wq * 16 + l15) * DHD + kc * 32 + quad * 8);
        qf1[kc] = *(const bf16x8*)(qbase + (size_t)(Tq1 * 64 + wq * 16 + l15) * DHD + kc * 32 + quad * 8);
    }

    // causal mask with PERMUTED kv positions
    bool dm[4][4];
#pragma unroll
    for (int ni = 0; ni < 4; ni++)
#pragma unroll
        for (int r = 0; r < 4; r++)
            dm[ni][r] = ((ni >> 1) * 32 + quad * 8 + (ni & 1) * 4 + r) > (wq * 16 + l15);

    const int srow = lane >> 2;
    const int gst = (((lane >> 5) & 1) << 1) | ((lane >> 3) & 1);
    const int scg = ((lane & 3) ^ gst) * 8;
    const int vrow = lane >> 3;
    const int vcg = ((lane & 7) ^ ((lane >> 3) & 7)) * 8;

    auto stage = [&](int kt, int buf) {
        if (grp == 0) {
#pragma unroll
            for (int i = 0; i < 4; i++)
                gl_lds16(kbase + (size_t)(kt * 64 + wq * 16 + srow) * DHD + i * 32 + scg,
                         &Ks[buf][i * 2048 + wq * 512]);
        } else {
#pragma unroll
            for (int i = 0; i < 4; i++)
                gl_lds16(vtbase + (size_t)(wq * 32 + i * 8 + vrow) * TT + kt * 64 + vcg,
                         &VTs[buf][wq * 2048 + i * 512]);
        }
    };

    stage(0, 0);

    const int gk = (((l15 >> 2) & 1) << 1) | ((l15 >> 1) & 1);

    f32x4 O0[8] = {}, O1[8] = {};
    float m0 = -INFINITY, l0 = 0.f, m1 = -INFINITY, l1 = 0.f;

    union PW { bf16x4 h[2]; bf16x8 v; };

    for (int kt = 0; kt <= ktmax_blk; kt++) {
        int cur = kt & 1;
        __syncthreads();
        if (kt < ktmax_blk) stage(kt + 1, cur ^ 1);

        if (kt > Tq1) continue;
        const bool a0 = (kt <= Tq0);

        f32x4 s0[4], s1[4];
        __builtin_amdgcn_s_setprio(1);
#pragma unroll
        for (int ni = 0; ni < 4; ni++) {
            int rr = (ni >> 1) * 32 + (l15 >> 2) * 8 + (ni & 1) * 4 + (l15 & 3);
            bf16x8 kfl[4];
#pragma unroll
            for (int kc = 0; kc < 4; kc++)
                kfl[kc] = *(const bf16x8*)(&Ks[cur][kc * 2048 + rr * 32 + ((quad ^ gk) * 8)]);
            f32x4 z1 = {};
#pragma unroll
            for (int kc = 0; kc < 4; kc++)
                z1 = __builtin_amdgcn_mfma_f32_16x16x32_bf16(kfl[kc], qf1[kc], z1, 0, 0, 0);
            s1[ni] = z1;
            if (a0) {
                f32x4 z0 = {};
#pragma unroll
                for (int kc = 0; kc < 4; kc++)
                    z0 = __builtin_amdgcn_mfma_f32_16x16x32_bf16(kfl[kc], qf0[kc], z0, 0, 0, 0);
                s0[ni] = z0;
            }
        }
        __builtin_amdgcn_s_setprio(0);

        PW pw0[2], pw1[2];
        {
            if (kt == Tq1) {
#pragma unroll
                for (int ni = 0; ni < 4; ni++)
#pragma unroll
                    for (int r = 0; r < 4; r++)
                        if (dm[ni][r]) s1[ni][r] = -INFINITY;
            }
            float mx = s1[0][0];
#pragma unroll
            for (int ni = 0; ni < 4; ni++)
#pragma unroll
                for (int r = 0; r < 4; r++) mx = fmaxf(mx, s1[ni][r]);
            mx = fmaxf(mx, __shfl_xor(mx, 16));
            mx = fmaxf(mx, __shfl_xor(mx, 32));
            float mold = m1;
            bool noresc = __all(mx <= mold + 8.f);   // T13 defer-max
            float mnew = noresc ? mold : fmaxf(mold, mx);
            float rs = 0.f;
#pragma unroll
            for (int ni = 0; ni < 4; ni++) {
                bf16x4 hv;
#pragma unroll
                for (int r = 0; r < 4; r++) {
                    float pe = __builtin_amdgcn_exp2f(s1[ni][r] - mnew);
                    hv[r] = (bf16)pe;
                    rs += pe;
                }
                pw1[ni >> 1].h[ni & 1] = hv;
            }
            rs += __shfl_xor(rs, 16);
            rs += __shfl_xor(rs, 32);
            if (!noresc) {
                float al = __builtin_amdgcn_exp2f(mold - mnew);
                l1 *= al;
#pragma unroll
                for (int dn = 0; dn < 8; dn++)
#pragma unroll
                    for (int r = 0; r < 4; r++) O1[dn][r] *= al;
                m1 = mnew;
            }
            l1 += rs;
        }
        if (a0) {
            if (kt == Tq0) {
#pragma unroll
                for (int ni = 0; ni < 4; ni++)
#pragma unroll
                    for (int r = 0; r < 4; r++)
                        if (dm[ni][r]) s0[ni][r] = -INFINITY;
            }
            float mx = s0[0][0];
#pragma unroll
            for (int ni = 0; ni < 4; ni++)
#pragma unroll
                for (int r = 0; r < 4; r++) mx = fmaxf(mx, s0[ni][r]);
            mx = fmaxf(mx, __shfl_xor(mx, 16));
            mx = fmaxf(mx, __shfl_xor(mx, 32));
            float mold = m0;
            bool noresc = __all(mx <= mold + 8.f);   // T13 defer-max
            float mnew = noresc ? mold : fmaxf(mold, mx);
            float rs = 0.f;
#pragma unroll
            for (int ni = 0; ni < 4; ni++) {
                bf16x4 hv;
#pragma unroll
                for (int r = 0; r < 4; r++) {
                    float pe = __builtin_amdgcn_exp2f(s0[ni][r] - mnew);
                    hv[r] = (bf16)pe;
                    rs += pe;
                }
                pw0[ni >> 1].h[ni & 1] = hv;
            }
            rs += __shfl_xor(rs, 16);
            rs += __shfl_xor(rs, 32);
            if (!noresc) {
                float al = __builtin_amdgcn_exp2f(mold - mnew);
                l0 *= al;
#pragma unroll
                for (int dn = 0; dn < 8; dn++)
#pragma unroll
                    for (int r = 0; r < 4; r++) O0[dn][r] *= al;
                m0 = mnew;
            }
            l0 += rs;
        }

        __builtin_amdgcn_s_setprio(1);
#pragma unroll
        for (int ni2 = 0; ni2 < 2; ni2++) {
            bf16x8 vfl[8];
#pragma unroll
            for (int dn = 0; dn < 8; dn++)
                vfl[dn] = *(const bf16x8*)(&VTs[cur][(dn * 16 + l15) * 64 +
                                                    (((ni2 * 4 + quad) ^ (l15 & 7)) * 8)]);
#pragma unroll
            for (int dn = 0; dn < 8; dn++)
                O1[dn] = __builtin_amdgcn_mfma_f32_16x16x32_bf16(vfl[dn], pw1[ni2].v, O1[dn], 0, 0, 0);
            if (a0) {
#pragma unroll
                for (int dn = 0; dn < 8; dn++)
                    O0[dn] = __builtin_amdgcn_mfma_f32_16x16x32_bf16(vfl[dn], pw0[ni2].v, O0[dn], 0, 0, 0);
            }
        }
        __builtin_amdgcn_s_setprio(0);
    }

    auto epi = [&](const f32x4* Oc, float lsum, int qt) {
        int qg = qt * 64 + wq * 16 + l15;
        float gi = gates[((size_t)b * TT + qg) * HH + h] / lsum;
#pragma unroll
        for (int dn = 0; dn < 8; dn++) {
            bf16x4 o;
#pragma unroll
            for (int r = 0; r < 4; r++) o[r] = (bf16)(Oc[dn][r] * gi);
            *(bf16x4*)(yb + ((size_t)(b * TT + qg) * HH + h) * DHD + dn * 16 + quad * 4) = o;
        }
    };
    epi(O0, l0, Tq0);
    epi(O1, l1, Tq1);
}

extern "C" void kernel_launch(void* const* d_in, const int* in_sizes, int n_in,
                              void* d_out, int out_size, void* d_ws, size_t ws_size,
                              hipStream_t stream) {
    const float* x    = (const float*)d_in[0];
    const float* cosb = (const float*)d_in[2];
    const float* sinb = (const float*)d_in[3];
    const float* v1   = (const float*)d_in[4];
    const float* Wq   = (const float*)d_in[5];
    const float* Wk   = (const float*)d_in[6];
    const float* Wv   = (const float*)d_in[7];
    const float* Wo   = (const float*)d_in[8];
    const float* gw   = (const float*)d_in[9];
    const float* lam  = (const float*)d_in[10];
    float* out = (float*)d_out;

    char* ws = (char*)d_ws;
    bf16* xb     = (bf16*)(ws);                   // 16,777,216 B (reused later by yb)
    bf16* wqkvb  = (bf16*)(ws + 16777216);        // 12,582,912
    bf16* wob    = (bf16*)(ws + 29360128);        //  8,388,608
    bf16* qb     = (bf16*)(ws + 79691776);        // 16,777,216
    bf16* kb     = (bf16*)(ws + 96468992);        //  4,194,304
    bf16* vtb    = (bf16*)(ws + 100663296);       //  4,194,304
    float* gts   = (float*)(ws + 104857600);      //    262,144
    bf16* yb     = xb;                            // alias: xb dead after QKV GEMM

    // converts
    cvt_bf16<<<4096, 256, 0, stream>>>(x, xb, 1048576);
    cvt_bf16<<<2048, 256, 0, stream>>>(Wq, wqkvb, 524288);
    cvt_bf16<<<512, 256, 0, stream>>>(Wk, wqkvb + 4194304, 131072);
    cvt_bf16<<<512, 256, 0, stream>>>(Wv, wqkvb + 5242880, 131072);
    cvt_bf16<<<2048, 256, 0, stream>>>(Wo, wob, 524288);

    // QKV projection + fused rmsnorm/rope/v-mix epilogues
    gemm_bt<1><<<dim3(12, 32), 512, 0, stream>>>(xb, wqkvb, 4096, NQKV, 2048,
                                                 nullptr, qb, kb, vtb, v1,
                                                 cosb, sinb, lam);
    // gates
    gatesk<<<256, 256, 0, stream>>>(x, gw, gts);
    // flash attention -- yb aliases xb
    fattn<<<256, 512, 0, stream>>>(qb, kb, vtb, gts, yb);
    // output projection
    gemm_bt<0><<<dim3(8, 32), 512, 0, stream>>>(yb, wob, 4096, 2048, 2048,
                                                out, nullptr, nullptr, nullptr,
                                                nullptr, nullptr, nullptr, nullptr);
    // v1 passthrough (second tuple output)
    (void)hipMemcpyAsync(out + 8388608, v1, (size_t)2097152 * sizeof(float),
                         hipMemcpyDeviceToDevice, stream);
}

// Round 5
// 303.301 us; speedup vs baseline: 1.0564x; 1.0564x over previous
//
#include <hip/hip_runtime.h>

typedef __bf16 bf16;
typedef __attribute__((ext_vector_type(8))) __bf16 bf16x8;
typedef __attribute__((ext_vector_type(4))) __bf16 bf16x4;
typedef __attribute__((ext_vector_type(4))) float f32x4;
typedef __attribute__((ext_vector_type(4))) short short4v;

// ---- constants for this problem ----
#define BB 2
#define TT 2048
#define DD 2048
#define HH 16
#define HKV 4
#define DHD 128
#define NQKV 3072   // H*DH + 2*HKV*DH

__device__ __forceinline__ void gl_lds16(const bf16* g, bf16* l) {
    __builtin_amdgcn_global_load_lds(
        (const __attribute__((address_space(1))) void*)g,
        (__attribute__((address_space(3))) void*)l, 16, 0, 0);
}

// ---------------- fp32 -> bf16 convert ----------------
__global__ void cvt_bf16(const float* __restrict__ src, bf16* __restrict__ dst, int n8) {
    int i = blockIdx.x * 256 + threadIdx.x;
    if (i >= n8) return;
    float4 a = ((const float4*)src)[i * 2];
    float4 b = ((const float4*)src)[i * 2 + 1];
    bf16x8 v;
    v[0] = (bf16)a.x; v[1] = (bf16)a.y; v[2] = (bf16)a.z; v[3] = (bf16)a.w;
    v[4] = (bf16)b.x; v[5] = (bf16)b.y; v[6] = (bf16)b.z; v[7] = (bf16)b.w;
    *(bf16x8*)(dst + (size_t)i * 8) = v;
}

// ---------------- GEMM: C = A(MxK) * Bw(NxK)^T, bf16 in, fp32 acc, BK=64 ----------------
// R10 = R7 structure (256 thr, 128x128 tile, 2 syncthreads/K-tile, multi-
// block/CU TLP) + two zero-sync-risk grafts validated in R9:
//  * T2 both-sides LDS swizzle (addressing only): staging source k-chunk
//    (lane&3)^((lane>>3)&3), fragment read slot quad^((l15>>1)&3). Kills the
//    4-way conflict on 64B-row chunk reads (same geometry as R6 fattn-K fix).
//  * T1 bijective XCD block swizzle (grid %8 == 0 for both launches).
// MODE 0: plain fp32 store. MODE 1: fused QKV epilogue (unchanged).
template <int MODE>
__global__ void gemm_bt(const bf16* __restrict__ A, const bf16* __restrict__ Bw,
                        int M, int N, int K,
                        float* __restrict__ Cout,
                        bf16* __restrict__ qb, bf16* __restrict__ kb,
                        bf16* __restrict__ vtb,
                        const float* __restrict__ v1,
                        const float* __restrict__ cosb,
                        const float* __restrict__ sinb,
                        const float* __restrict__ lamp) {
    constexpr int SMEM_ELE = (MODE == 1) ? 17920 : 16384;  // bf16 elements
    __shared__ bf16 smem[SMEM_ELE];
    bf16* As = smem;          // [kc2:2][rc:8][16 rows][32 k] = 8192 ele
    bf16* Bs = smem + 8192;
    const int tid = threadIdx.x;
    const int w = tid >> 6, lane = tid & 63;
    const int l15 = lane & 15, quad = lane >> 4;

    // T1: bijective XCD-aware block swizzle (nwg % 8 == 0 for our grids)
    const int nwg = gridDim.x * gridDim.y;
    int wg = blockIdx.y * gridDim.x + blockIdx.x;
    int swz = (wg & 7) * (nwg >> 3) + (wg >> 3);
    const int bx = swz % gridDim.x, by = swz / gridDim.x;
    const int m0 = by * 128, n0 = bx * 128;
    const int wm = (w & 1) * 64, wn = (w >> 1) * 64;

    f32x4 acc[4][4] = {};
    const int lrow = lane >> 2;                          // 0..15 row within chunk
    const int scol = ((lane & 3) ^ ((lane >> 3) & 3)) * 8;  // T2 source-side swizzle
    const int xs = (quad ^ ((l15 >> 1) & 3)) * 8;           // T2 read-side swizzle

    for (int k0 = 0; k0 < K; k0 += 64) {
#pragma unroll
        for (int i = 0; i < 4; i++) {
            int c = w * 4 + i;           // 0..15
            int kc2 = c >> 3, rc = c & 7;
            int row = rc * 16 + lrow;
            int kk = k0 + kc2 * 32 + scol;
            gl_lds16(A + (size_t)(m0 + row) * K + kk, As + c * 512);
            gl_lds16(Bw + (size_t)(n0 + row) * K + kk, Bs + c * 512);
        }
        __syncthreads();
#pragma unroll
        for (int kc2 = 0; kc2 < 2; kc2++) {
            bf16x8 af[4], bfr[4];
#pragma unroll
            for (int mi = 0; mi < 4; mi++)
                af[mi] = *(const bf16x8*)(As + kc2 * 4096 + ((wm >> 4) + mi) * 512 + l15 * 32 + xs);
#pragma unroll
            for (int ni = 0; ni < 4; ni++)
                bfr[ni] = *(const bf16x8*)(Bs + kc2 * 4096 + ((wn >> 4) + ni) * 512 + l15 * 32 + xs);
#pragma unroll
            for (int mi = 0; mi < 4; mi++)
#pragma unroll
                for (int ni = 0; ni < 4; ni++)
                    acc[mi][ni] = __builtin_amdgcn_mfma_f32_16x16x32_bf16(af[mi], bfr[ni], acc[mi][ni], 0, 0, 0);
        }
        __syncthreads();
    }

    if constexpr (MODE == 0) {
#pragma unroll
        for (int mi = 0; mi < 4; mi++)
#pragma unroll
            for (int ni = 0; ni < 4; ni++)
#pragma unroll
                for (int r = 0; r < 4; r++) {
                    int m = m0 + wm + mi * 16 + quad * 4 + r;
                    int n = n0 + wn + ni * 16 + l15;
                    Cout[(size_t)m * N + n] = acc[mi][ni][r];
                }
    } else {
        const int hid = n0 >> 7;         // 0..23
        const int b = m0 >> 11;
        const int t0 = m0 & (TT - 1);
        bf16* ep = smem;                 // [128 rows][136] transpose buffer

        if (hid < 20) {
            // ---- rmsnorm partials (per row, across the 128-col head) ----
            float* ssum = (float*)(smem + 17408);   // [2][128] fp32
            float ssq[4][4];
#pragma unroll
            for (int mi = 0; mi < 4; mi++)
#pragma unroll
                for (int r = 0; r < 4; r++) {
                    float s = 0.f;
#pragma unroll
                    for (int ni = 0; ni < 4; ni++) {
                        float v = acc[mi][ni][r];
                        s += v * v;
                    }
                    s += __shfl_xor(s, 1);
                    s += __shfl_xor(s, 2);
                    s += __shfl_xor(s, 4);
                    s += __shfl_xor(s, 8);
                    ssq[mi][r] = s;
                }
            if (l15 == 0) {
#pragma unroll
                for (int mi = 0; mi < 4; mi++)
#pragma unroll
                    for (int r = 0; r < 4; r++)
                        ssum[(wn >> 6) * 128 + wm + mi * 16 + quad * 4 + r] = ssq[mi][r];
            }
            __syncthreads();
            const float QSCALE = 0.08838834764831845f * 1.4426950408889634f;
            float rn[4][4];
#pragma unroll
            for (int mi = 0; mi < 4; mi++)
#pragma unroll
                for (int r = 0; r < 4; r++) {
                    int row = wm + mi * 16 + quad * 4 + r;
                    float ss = ssum[row] + ssum[128 + row];
                    float rv = rsqrtf(ss * (1.f / 128.f) + 1e-6f);
                    if (hid < HH) rv *= QSCALE;
                    rn[mi][r] = rv;
                }
            // ---- rope -> ep[t_local][outcol] ----
#pragma unroll
            for (int mi = 0; mi < 4; mi++)
#pragma unroll
                for (int ni = 0; ni < 4; ni++)
#pragma unroll
                    for (int r = 0; r < 4; r++) {
                        float sv = acc[mi][ni][r] * rn[mi][r];
                        float pv = __shfl_xor(sv, 1);
                        int nl = wn + ni * 16 + l15;       // 0..127
                        int j = nl >> 1;                   // 0..63
                        int tl = wm + mi * 16 + quad * 4 + r;
                        float c = cosb[(size_t)(t0 + tl) * 64 + j];
                        float s = sinb[(size_t)(t0 + tl) * 64 + j];
                        float o = (nl & 1) ? (sv * c + pv * s) : (sv * c - pv * s);
                        int oc = (nl & 1) ? (64 + j) : j;
                        ep[tl * 136 + oc] = (bf16)o;
                    }
            __syncthreads();
            bf16* dst = (hid < HH)
                ? (qb + ((size_t)(b * HH + hid) * TT + t0) * DHD)
                : (kb + ((size_t)(b * HKV + (hid - HH)) * TT + t0) * DHD);
            int tl = tid >> 1, half = tid & 1;
#pragma unroll
            for (int c8 = 0; c8 < 8; c8++)
                *(bf16x8*)(dst + (size_t)tl * DHD + half * 64 + c8 * 8) =
                    *(const bf16x8*)(ep + tl * 136 + half * 64 + c8 * 8);
        } else {
            // ---- v: mix with v1, transpose -> vtb (B,HKV,DH,T) ----
            float lam = lamp[0];
            int vh = hid - 20;
            const float* v1b = v1 + ((size_t)(b * HKV + vh) * TT) * DHD;
#pragma unroll
            for (int mi = 0; mi < 4; mi++)
#pragma unroll
                for (int ni = 0; ni < 4; ni++)
#pragma unroll
                    for (int r = 0; r < 4; r++) {
                        int d = wn + ni * 16 + l15;
                        int tl = wm + mi * 16 + quad * 4 + r;
                        float val = acc[mi][ni][r];
                        float vm = val + lam * (v1b[(size_t)(t0 + tl) * DHD + d] - val);
                        ep[d * 136 + tl] = (bf16)vm;
                    }
            __syncthreads();
            bf16* dstv = vtb + ((size_t)(b * HKV + vh) * DHD) * TT + t0;
            int dd = tid >> 1, half = tid & 1;
#pragma unroll
            for (int c8 = 0; c8 < 8; c8++)
                *(bf16x8*)(dstv + (size_t)dd * TT + half * 64 + c8 * 8) =
                    *(const bf16x8*)(ep + dd * 136 + half * 64 + c8 * 8);
        }
    }
}

// ---------------- gates = sigmoid(x[:, :16] @ gate_w^T) ----------------
__global__ void gatesk(const float* __restrict__ x, const float* __restrict__ gw,
                       float* __restrict__ gates) {
    __shared__ float gws[256];
    gws[threadIdx.x] = gw[threadIdx.x];
    __syncthreads();
    int idx = blockIdx.x * 256 + threadIdx.x;
    int h = idx & 15, token = idx >> 4;
    const float* xr = x + (size_t)token * DD;
    float z = 0.f;
#pragma unroll
    for (int j = 0; j < 16; j++) z += xr[j] * gws[h * 16 + j];
    gates[idx] = 1.f / (1.f + __expf(-z));
}

// ---------------- flash attention (unchanged from R7) ----------------
__global__ __launch_bounds__(512, 2) void fattn(const bf16* __restrict__ qbuf,
                                                const bf16* __restrict__ kbuf,
                                                const bf16* __restrict__ vt,
                                                const float* __restrict__ gates,
                                                bf16* __restrict__ yb) {
    __shared__ bf16 Ks[2][4 * 2048];
    __shared__ bf16 VTs[2][8192];     // [128 d][64 k], slot16 ^= (d&7)

    const int bid = blockIdx.x;          // 256 blocks
    const int bh = bid & 31;             // b*16+h
    const int g = bid >> 5;              // 0..7
    const int h = bh & 15, b = bh >> 4;
    const int hk = h >> 2;
    const int tid = threadIdx.x, w = tid >> 6, lane = tid & 63;
    const int wq = w & 3, grp = w >> 2;
    const int l15 = lane & 15, quad = lane >> 4;

    const bf16* qbase = qbuf + ((size_t)(b * HH + h) * TT) * DHD;
    const bf16* kbase = kbuf + ((size_t)(b * HKV + hk) * TT) * DHD;
    const bf16* vtbase = vt + ((size_t)(b * HKV + hk) * DHD) * TT;

    const int Tq0 = grp ? (15 - g) : g;
    const int Tq1 = grp ? (16 + g) : (31 - g);
    const int ktmax_blk = 31 - g;

    bf16x8 qf0[4], qf1[4];
#pragma unroll
    for (int kc = 0; kc < 4; kc++) {
        qf0[kc] = *(const bf16x8*)(qbase + (size_t)(Tq0 * 64 + wq * 16 + l15) * DHD + kc * 32 + quad * 8);
        qf1[kc] = *(const bf16x8*)(qbase + (size_t)(Tq1 * 64 + wq * 16 + l15) * DHD + kc * 32 + quad * 8);
    }

    // causal mask with PERMUTED kv positions
    bool dm[4][4];
#pragma unroll
    for (int ni = 0; ni < 4; ni++)
#pragma unroll
        for (int r = 0; r < 4; r++)
            dm[ni][r] = ((ni >> 1) * 32 + quad * 8 + (ni & 1) * 4 + r) > (wq * 16 + l15);

    const int srow = lane >> 2;
    const int gst = (((lane >> 5) & 1) << 1) | ((lane >> 3) & 1);
    const int scg = ((lane & 3) ^ gst) * 8;
    const int vrow = lane >> 3;
    const int vcg = ((lane & 7) ^ ((lane >> 3) & 7)) * 8;

    auto stage = [&](int kt, int buf) {
        if (grp == 0) {
#pragma unroll
            for (int i = 0; i < 4; i++)
                gl_lds16(kbase + (size_t)(kt * 64 + wq * 16 + srow) * DHD + i * 32 + scg,
                         &Ks[buf][i * 2048 + wq * 512]);
        } else {
#pragma unroll
            for (int i = 0; i < 4; i++)
                gl_lds16(vtbase + (size_t)(wq * 32 + i * 8 + vrow) * TT + kt * 64 + vcg,
                         &VTs[buf][wq * 2048 + i * 512]);
        }
    };

    stage(0, 0);

    const int gk = (((l15 >> 2) & 1) << 1) | ((l15 >> 1) & 1);

    f32x4 O0[8] = {}, O1[8] = {};
    float m0 = -INFINITY, l0 = 0.f, m1 = -INFINITY, l1 = 0.f;

    union PW { bf16x4 h[2]; bf16x8 v; };

    for (int kt = 0; kt <= ktmax_blk; kt++) {
        int cur = kt & 1;
        __syncthreads();
        if (kt < ktmax_blk) stage(kt + 1, cur ^ 1);

        if (kt > Tq1) continue;
        const bool a0 = (kt <= Tq0);

        f32x4 s0[4], s1[4];
        __builtin_amdgcn_s_setprio(1);
#pragma unroll
        for (int ni = 0; ni < 4; ni++) {
            int rr = (ni >> 1) * 32 + (l15 >> 2) * 8 + (ni & 1) * 4 + (l15 & 3);
            bf16x8 kfl[4];
#pragma unroll
            for (int kc = 0; kc < 4; kc++)
                kfl[kc] = *(const bf16x8*)(&Ks[cur][kc * 2048 + rr * 32 + ((quad ^ gk) * 8)]);
            f32x4 z1 = {};
#pragma unroll
            for (int kc = 0; kc < 4; kc++)
                z1 = __builtin_amdgcn_mfma_f32_16x16x32_bf16(kfl[kc], qf1[kc], z1, 0, 0, 0);
            s1[ni] = z1;
            if (a0) {
                f32x4 z0 = {};
#pragma unroll
                for (int kc = 0; kc < 4; kc++)
                    z0 = __builtin_amdgcn_mfma_f32_16x16x32_bf16(kfl[kc], qf0[kc], z0, 0, 0, 0);
                s0[ni] = z0;
            }
        }
        __builtin_amdgcn_s_setprio(0);

        PW pw0[2], pw1[2];
        {
            if (kt == Tq1) {
#pragma unroll
                for (int ni = 0; ni < 4; ni++)
#pragma unroll
                    for (int r = 0; r < 4; r++)
                        if (dm[ni][r]) s1[ni][r] = -INFINITY;
            }
            float mx = s1[0][0];
#pragma unroll
            for (int ni = 0; ni < 4; ni++)
#pragma unroll
                for (int r = 0; r < 4; r++) mx = fmaxf(mx, s1[ni][r]);
            mx = fmaxf(mx, __shfl_xor(mx, 16));
            mx = fmaxf(mx, __shfl_xor(mx, 32));
            float mold = m1;
            bool noresc = __all(mx <= mold + 8.f);   // T13 defer-max
            float mnew = noresc ? mold : fmaxf(mold, mx);
            float rs = 0.f;
#pragma unroll
            for (int ni = 0; ni < 4; ni++) {
                bf16x4 hv;
#pragma unroll
                for (int r = 0; r < 4; r++) {
                    float pe = __builtin_amdgcn_exp2f(s1[ni][r] - mnew);
                    hv[r] = (bf16)pe;
                    rs += pe;
                }
                pw1[ni >> 1].h[ni & 1] = hv;
            }
            rs += __shfl_xor(rs, 16);
            rs += __shfl_xor(rs, 32);
            if (!noresc) {
                float al = __builtin_amdgcn_exp2f(mold - mnew);
                l1 *= al;
#pragma unroll
                for (int dn = 0; dn < 8; dn++)
#pragma unroll
                    for (int r = 0; r < 4; r++) O1[dn][r] *= al;
                m1 = mnew;
            }
            l1 += rs;
        }
        if (a0) {
            if (kt == Tq0) {
#pragma unroll
                for (int ni = 0; ni < 4; ni++)
#pragma unroll
                    for (int r = 0; r < 4; r++)
                        if (dm[ni][r]) s0[ni][r] = -INFINITY;
            }
            float mx = s0[0][0];
#pragma unroll
            for (int ni = 0; ni < 4; ni++)
#pragma unroll
                for (int r = 0; r < 4; r++) mx = fmaxf(mx, s0[ni][r]);
            mx = fmaxf(mx, __shfl_xor(mx, 16));
            mx = fmaxf(mx, __shfl_xor(mx, 32));
            float mold = m0;
            bool noresc = __all(mx <= mold + 8.f);   // T13 defer-max
            float mnew = noresc ? mold : fmaxf(mold, mx);
            float rs = 0.f;
#pragma unroll
            for (int ni = 0; ni < 4; ni++) {
                bf16x4 hv;
#pragma unroll
                for (int r = 0; r < 4; r++) {
                    float pe = __builtin_amdgcn_exp2f(s0[ni][r] - mnew);
                    hv[r] = (bf16)pe;
                    rs += pe;
                }
                pw0[ni >> 1].h[ni & 1] = hv;
            }
            rs += __shfl_xor(rs, 16);
            rs += __shfl_xor(rs, 32);
            if (!noresc) {
                float al = __builtin_amdgcn_exp2f(mold - mnew);
                l0 *= al;
#pragma unroll
                for (int dn = 0; dn < 8; dn++)
#pragma unroll
                    for (int r = 0; r < 4; r++) O0[dn][r] *= al;
                m0 = mnew;
            }
            l0 += rs;
        }

        __builtin_amdgcn_s_setprio(1);
#pragma unroll
        for (int ni2 = 0; ni2 < 2; ni2++) {
            bf16x8 vfl[8];
#pragma unroll
            for (int dn = 0; dn < 8; dn++)
                vfl[dn] = *(const bf16x8*)(&VTs[cur][(dn * 16 + l15) * 64 +
                                                    (((ni2 * 4 + quad) ^ (l15 & 7)) * 8)]);
#pragma unroll
            for (int dn = 0; dn < 8; dn++)
                O1[dn] = __builtin_amdgcn_mfma_f32_16x16x32_bf16(vfl[dn], pw1[ni2].v, O1[dn], 0, 0, 0);
            if (a0) {
#pragma unroll
                for (int dn = 0; dn < 8; dn++)
                    O0[dn] = __builtin_amdgcn_mfma_f32_16x16x32_bf16(vfl[dn], pw0[ni2].v, O0[dn], 0, 0, 0);
            }
        }
        __builtin_amdgcn_s_setprio(0);
    }

    auto epi = [&](const f32x4* Oc, float lsum, int qt) {
        int qg = qt * 64 + wq * 16 + l15;
        float gi = gates[((size_t)b * TT + qg) * HH + h] / lsum;
#pragma unroll
        for (int dn = 0; dn < 8; dn++) {
            bf16x4 o;
#pragma unroll
            for (int r = 0; r < 4; r++) o[r] = (bf16)(Oc[dn][r] * gi);
            *(bf16x4*)(yb + ((size_t)(b * TT + qg) * HH + h) * DHD + dn * 16 + quad * 4) = o;
        }
    };
    epi(O0, l0, Tq0);
    epi(O1, l1, Tq1);
}

extern "C" void kernel_launch(void* const* d_in, const int* in_sizes, int n_in,
                              void* d_out, int out_size, void* d_ws, size_t ws_size,
                              hipStream_t stream) {
    const float* x    = (const float*)d_in[0];
    const float* cosb = (const float*)d_in[2];
    const float* sinb = (const float*)d_in[3];
    const float* v1   = (const float*)d_in[4];
    const float* Wq   = (const float*)d_in[5];
    const float* Wk   = (const float*)d_in[6];
    const float* Wv   = (const float*)d_in[7];
    const float* Wo   = (const float*)d_in[8];
    const float* gw   = (const float*)d_in[9];
    const float* lam  = (const float*)d_in[10];
    float* out = (float*)d_out;

    char* ws = (char*)d_ws;
    bf16* xb     = (bf16*)(ws);                   // 16,777,216 B (reused later by yb)
    bf16* wqkvb  = (bf16*)(ws + 16777216);        // 12,582,912
    bf16* wob    = (bf16*)(ws + 29360128);        //  8,388,608
    bf16* qb     = (bf16*)(ws + 79691776);        // 16,777,216
    bf16* kb     = (bf16*)(ws + 96468992);        //  4,194,304
    bf16* vtb    = (bf16*)(ws + 100663296);       //  4,194,304
    float* gts   = (float*)(ws + 104857600);      //    262,144
    bf16* yb     = xb;                            // alias: xb dead after QKV GEMM

    // converts
    cvt_bf16<<<4096, 256, 0, stream>>>(x, xb, 1048576);
    cvt_bf16<<<2048, 256, 0, stream>>>(Wq, wqkvb, 524288);
    cvt_bf16<<<512, 256, 0, stream>>>(Wk, wqkvb + 4194304, 131072);
    cvt_bf16<<<512, 256, 0, stream>>>(Wv, wqkvb + 5242880, 131072);
    cvt_bf16<<<2048, 256, 0, stream>>>(Wo, wob, 524288);

    // QKV projection + fused rmsnorm/rope/v-mix epilogues
    gemm_bt<1><<<dim3(24, 32), 256, 0, stream>>>(xb, wqkvb, 4096, NQKV, 2048,
                                                 nullptr, qb, kb, vtb, v1,
                                                 cosb, sinb, lam);
    // gates
    gatesk<<<256, 256, 0, stream>>>(x, gw, gts);
    // flash attention -- yb aliases xb
    fattn<<<256, 512, 0, stream>>>(qb, kb, vtb, gts, yb);
    // output projection
    gemm_bt<0><<<dim3(16, 32), 256, 0, stream>>>(yb, wob, 4096, 2048, 2048,
                                                 out, nullptr, nullptr, nullptr,
                                                 nullptr, nullptr, nullptr, nullptr);
    // v1 passthrough (second tuple output)
    (void)hipMemcpyAsync(out + 8388608, v1, (size_t)2097152 * sizeof(float),
                         hipMemcpyDeviceToDevice, stream);
}

// Round 6
// 292.521 us; speedup vs baseline: 1.0954x; 1.0369x over previous
//
#include <hip/hip_runtime.h>

typedef __bf16 bf16;
typedef __attribute__((ext_vector_type(8))) __bf16 bf16x8;
typedef __attribute__((ext_vector_type(4))) __bf16 bf16x4;
typedef __attribute__((ext_vector_type(4))) float f32x4;
typedef __attribute__((ext_vector_type(4))) short short4v;

// ---- constants for this problem ----
#define BB 2
#define TT 2048
#define DD 2048
#define HH 16
#define HKV 4
#define DHD 128
#define NQKV 3072   // H*DH + 2*HKV*DH

__device__ __forceinline__ void gl_lds16(const bf16* g, bf16* l) {
    __builtin_amdgcn_global_load_lds(
        (const __attribute__((address_space(1))) void*)g,
        (__attribute__((address_space(3))) void*)l, 16, 0, 0);
}

// ---------------- fused fp32->bf16 converts + gates ----------------
// R11: one kernel replaces 5 cvt launches + gatesk (launch-gap elimination).
// blocks [0,4096):    x -> xb; block == one token row; gates computed inline
// blocks [4096,6144): Wq -> wqkvb
// blocks [6144,6656): Wk -> wqkvb+4194304
// blocks [6656,7168): Wv -> wqkvb+5242880
// blocks [7168,9216): Wo -> wob
__global__ void cvt_fuse(const float* __restrict__ x, const float* __restrict__ Wq,
                         const float* __restrict__ Wk, const float* __restrict__ Wv,
                         const float* __restrict__ Wo, const float* __restrict__ gw,
                         bf16* __restrict__ xb, bf16* __restrict__ wqkvb,
                         bf16* __restrict__ wob, float* __restrict__ gates) {
    const int blk = blockIdx.x, tid = threadIdx.x;
    const float* src; bf16* dst; int i;
    const bool isx = blk < 4096;
    if (isx)              { src = x;  dst = xb;              i = blk * 256 + tid; }
    else if (blk < 6144)  { src = Wq; dst = wqkvb;           i = (blk - 4096) * 256 + tid; }
    else if (blk < 6656)  { src = Wk; dst = wqkvb + 4194304; i = (blk - 6144) * 256 + tid; }
    else if (blk < 7168)  { src = Wv; dst = wqkvb + 5242880; i = (blk - 6656) * 256 + tid; }
    else                  { src = Wo; dst = wob;             i = (blk - 7168) * 256 + tid; }
    float4 a = ((const float4*)src)[i * 2];
    float4 b = ((const float4*)src)[i * 2 + 1];
    bf16x8 v;
    v[0] = (bf16)a.x; v[1] = (bf16)a.y; v[2] = (bf16)a.z; v[3] = (bf16)a.w;
    v[4] = (bf16)b.x; v[5] = (bf16)b.y; v[6] = (bf16)b.z; v[7] = (bf16)b.w;
    *(bf16x8*)(dst + (size_t)i * 8) = v;

    if (isx) {   // block-uniform branch; gates for this token
        __shared__ float xs16[16];
        __shared__ float gws[256];
        gws[tid] = gw[tid];
        if (tid < 2) {
            xs16[tid * 8 + 0] = a.x; xs16[tid * 8 + 1] = a.y;
            xs16[tid * 8 + 2] = a.z; xs16[tid * 8 + 3] = a.w;
            xs16[tid * 8 + 4] = b.x; xs16[tid * 8 + 5] = b.y;
            xs16[tid * 8 + 6] = b.z; xs16[tid * 8 + 7] = b.w;
        }
        __syncthreads();
        if (tid < 16) {
            float z = 0.f;
#pragma unroll
            for (int j = 0; j < 16; j++) z += xs16[j] * gws[tid * 16 + j];
            gates[blk * 16 + tid] = 1.f / (1.f + __expf(-z));
        }
    }
}

// ---------------- GEMM: C = A(MxK) * Bw(NxK)^T, bf16 in, fp32 acc, BK=64 ----------------
// R10 structure (frozen): 256 thr, 128x128 tile, 2 syncthreads/K-tile, multi-
// block/CU TLP + T2 both-sides LDS swizzle + T1 bijective XCD block swizzle.
// MODE 0: plain fp32 store. MODE 1: fused QKV epilogue.
template <int MODE>
__global__ void gemm_bt(const bf16* __restrict__ A, const bf16* __restrict__ Bw,
                        int M, int N, int K,
                        float* __restrict__ Cout,
                        bf16* __restrict__ qb, bf16* __restrict__ kb,
                        bf16* __restrict__ vtb,
                        const float* __restrict__ v1,
                        const float* __restrict__ cosb,
                        const float* __restrict__ sinb,
                        const float* __restrict__ lamp) {
    constexpr int SMEM_ELE = (MODE == 1) ? 17920 : 16384;  // bf16 elements
    __shared__ bf16 smem[SMEM_ELE];
    bf16* As = smem;          // [kc2:2][rc:8][16 rows][32 k] = 8192 ele
    bf16* Bs = smem + 8192;
    const int tid = threadIdx.x;
    const int w = tid >> 6, lane = tid & 63;
    const int l15 = lane & 15, quad = lane >> 4;

    // T1: bijective XCD-aware block swizzle (nwg % 8 == 0 for our grids)
    const int nwg = gridDim.x * gridDim.y;
    int wg = blockIdx.y * gridDim.x + blockIdx.x;
    int swz = (wg & 7) * (nwg >> 3) + (wg >> 3);
    const int bx = swz % gridDim.x, by = swz / gridDim.x;
    const int m0 = by * 128, n0 = bx * 128;
    const int wm = (w & 1) * 64, wn = (w >> 1) * 64;

    f32x4 acc[4][4] = {};
    const int lrow = lane >> 2;                          // 0..15 row within chunk
    const int scol = ((lane & 3) ^ ((lane >> 3) & 3)) * 8;  // T2 source-side swizzle
    const int xs = (quad ^ ((l15 >> 1) & 3)) * 8;           // T2 read-side swizzle

    for (int k0 = 0; k0 < K; k0 += 64) {
#pragma unroll
        for (int i = 0; i < 4; i++) {
            int c = w * 4 + i;           // 0..15
            int kc2 = c >> 3, rc = c & 7;
            int row = rc * 16 + lrow;
            int kk = k0 + kc2 * 32 + scol;
            gl_lds16(A + (size_t)(m0 + row) * K + kk, As + c * 512);
            gl_lds16(Bw + (size_t)(n0 + row) * K + kk, Bs + c * 512);
        }
        __syncthreads();
#pragma unroll
        for (int kc2 = 0; kc2 < 2; kc2++) {
            bf16x8 af[4], bfr[4];
#pragma unroll
            for (int mi = 0; mi < 4; mi++)
                af[mi] = *(const bf16x8*)(As + kc2 * 4096 + ((wm >> 4) + mi) * 512 + l15 * 32 + xs);
#pragma unroll
            for (int ni = 0; ni < 4; ni++)
                bfr[ni] = *(const bf16x8*)(Bs + kc2 * 4096 + ((wn >> 4) + ni) * 512 + l15 * 32 + xs);
#pragma unroll
            for (int mi = 0; mi < 4; mi++)
#pragma unroll
                for (int ni = 0; ni < 4; ni++)
                    acc[mi][ni] = __builtin_amdgcn_mfma_f32_16x16x32_bf16(af[mi], bfr[ni], acc[mi][ni], 0, 0, 0);
        }
        __syncthreads();
    }

    if constexpr (MODE == 0) {
#pragma unroll
        for (int mi = 0; mi < 4; mi++)
#pragma unroll
            for (int ni = 0; ni < 4; ni++)
#pragma unroll
                for (int r = 0; r < 4; r++) {
                    int m = m0 + wm + mi * 16 + quad * 4 + r;
                    int n = n0 + wn + ni * 16 + l15;
                    Cout[(size_t)m * N + n] = acc[mi][ni][r];
                }
    } else {
        const int hid = n0 >> 7;         // 0..23
        const int b = m0 >> 11;
        const int t0 = m0 & (TT - 1);
        bf16* ep = smem;                 // [128 rows][136] transpose buffer

        if (hid < 20) {
            // ---- rmsnorm partials (per row, across the 128-col head) ----
            float* ssum = (float*)(smem + 17408);   // [2][128] fp32
            float ssq[4][4];
#pragma unroll
            for (int mi = 0; mi < 4; mi++)
#pragma unroll
                for (int r = 0; r < 4; r++) {
                    float s = 0.f;
#pragma unroll
                    for (int ni = 0; ni < 4; ni++) {
                        float v = acc[mi][ni][r];
                        s += v * v;
                    }
                    s += __shfl_xor(s, 1);
                    s += __shfl_xor(s, 2);
                    s += __shfl_xor(s, 4);
                    s += __shfl_xor(s, 8);
                    ssq[mi][r] = s;
                }
            if (l15 == 0) {
#pragma unroll
                for (int mi = 0; mi < 4; mi++)
#pragma unroll
                    for (int r = 0; r < 4; r++)
                        ssum[(wn >> 6) * 128 + wm + mi * 16 + quad * 4 + r] = ssq[mi][r];
            }
            __syncthreads();
            const float QSCALE = 0.08838834764831845f * 1.4426950408889634f;
            float rn[4][4];
#pragma unroll
            for (int mi = 0; mi < 4; mi++)
#pragma unroll
                for (int r = 0; r < 4; r++) {
                    int row = wm + mi * 16 + quad * 4 + r;
                    float ss = ssum[row] + ssum[128 + row];
                    float rv = rsqrtf(ss * (1.f / 128.f) + 1e-6f);
                    if (hid < HH) rv *= QSCALE;
                    rn[mi][r] = rv;
                }
            // ---- rope -> ep[t_local][outcol] ----
#pragma unroll
            for (int mi = 0; mi < 4; mi++)
#pragma unroll
                for (int ni = 0; ni < 4; ni++)
#pragma unroll
                    for (int r = 0; r < 4; r++) {
                        float sv = acc[mi][ni][r] * rn[mi][r];
                        float pv = __shfl_xor(sv, 1);
                        int nl = wn + ni * 16 + l15;       // 0..127
                        int j = nl >> 1;                   // 0..63
                        int tl = wm + mi * 16 + quad * 4 + r;
                        float c = cosb[(size_t)(t0 + tl) * 64 + j];
                        float s = sinb[(size_t)(t0 + tl) * 64 + j];
                        float o = (nl & 1) ? (sv * c + pv * s) : (sv * c - pv * s);
                        int oc = (nl & 1) ? (64 + j) : j;
                        ep[tl * 136 + oc] = (bf16)o;
                    }
            __syncthreads();
            bf16* dst = (hid < HH)
                ? (qb + ((size_t)(b * HH + hid) * TT + t0) * DHD)
                : (kb + ((size_t)(b * HKV + (hid - HH)) * TT + t0) * DHD);
            int tl = tid >> 1, half = tid & 1;
#pragma unroll
            for (int c8 = 0; c8 < 8; c8++)
                *(bf16x8*)(dst + (size_t)tl * DHD + half * 64 + c8 * 8) =
                    *(const bf16x8*)(ep + tl * 136 + half * 64 + c8 * 8);
        } else {
            // ---- v: mix with v1, transpose -> vtb (B,HKV,DH,T) ----
            float lam = lamp[0];
            int vh = hid - 20;
            const float* v1b = v1 + ((size_t)(b * HKV + vh) * TT) * DHD;
#pragma unroll
            for (int mi = 0; mi < 4; mi++)
#pragma unroll
            for (int ni = 0; ni < 4; ni++)
#pragma unroll
                for (int r = 0; r < 4; r++) {
                    int d = wn + ni * 16 + l15;
                    int tl = wm + mi * 16 + quad * 4 + r;
                    float val = acc[mi][ni][r];
                    float vm = val + lam * (v1b[(size_t)(t0 + tl) * DHD + d] - val);
                    ep[d * 136 + tl] = (bf16)vm;
                }
            __syncthreads();
            bf16* dstv = vtb + ((size_t)(b * HKV + vh) * DHD) * TT + t0;
            int dd = tid >> 1, half = tid & 1;
#pragma unroll
            for (int c8 = 0; c8 < 8; c8++)
                *(bf16x8*)(dstv + (size_t)dd * TT + half * 64 + c8 * 8) =
                    *(const bf16x8*)(ep + dd * 136 + half * 64 + c8 * 8);
        }
    }
}

// ---------------- flash attention (R7 body; + v1 passthrough copy) ----------------
__global__ __launch_bounds__(512, 2) void fattn(const bf16* __restrict__ qbuf,
                                                const bf16* __restrict__ kbuf,
                                                const bf16* __restrict__ vt,
                                                const float* __restrict__ gates,
                                                bf16* __restrict__ yb,
                                                const float* __restrict__ v1f,
                                                float* __restrict__ vout) {
    __shared__ bf16 Ks[2][4 * 2048];
    __shared__ bf16 VTs[2][8192];     // [128 d][64 k], slot16 ^= (d&7)

    const int bid = blockIdx.x;          // 256 blocks
    const int bh = bid & 31;             // b*16+h
    const int g = bid >> 5;              // 0..7
    const int h = bh & 15, b = bh >> 4;
    const int hk = h >> 2;
    const int tid = threadIdx.x, w = tid >> 6, lane = tid & 63;
    const int wq = w & 3, grp = w >> 2;
    const int l15 = lane & 15, quad = lane >> 4;

    // v1 passthrough: each block copies a disjoint 32 KB chunk (replaces the
    // trailing hipMemcpyAsync launch; fattn is ~5% HBM so this is free BW).
    {
        const float4* s4 = (const float4*)(v1f + (size_t)bid * 8192);
        float4* d4 = (float4*)(vout + (size_t)bid * 8192);
#pragma unroll
        for (int i = 0; i < 4; i++) d4[tid + i * 512] = s4[tid + i * 512];
    }

    const bf16* qbase = qbuf + ((size_t)(b * HH + h) * TT) * DHD;
    const bf16* kbase = kbuf + ((size_t)(b * HKV + hk) * TT) * DHD;
    const bf16* vtbase = vt + ((size_t)(b * HKV + hk) * DHD) * TT;

    const int Tq0 = grp ? (15 - g) : g;
    const int Tq1 = grp ? (16 + g) : (31 - g);
    const int ktmax_blk = 31 - g;

    bf16x8 qf0[4], qf1[4];
#pragma unroll
    for (int kc = 0; kc < 4; kc++) {
        qf0[kc] = *(const bf16x8*)(qbase + (size_t)(Tq0 * 64 + wq * 16 + l15) * DHD + kc * 32 + quad * 8);
        qf1[kc] = *(const bf16x8*)(qbase + (size_t)(Tq1 * 64 + wq * 16 + l15) * DHD + kc * 32 + quad * 8);
    }

    // causal mask with PERMUTED kv positions
    bool dm[4][4];
#pragma unroll
    for (int ni = 0; ni < 4; ni++)
#pragma unroll
        for (int r = 0; r < 4; r++)
            dm[ni][r] = ((ni >> 1) * 32 + quad * 8 + (ni & 1) * 4 + r) > (wq * 16 + l15);

    const int srow = lane >> 2;
    const int gst = (((lane >> 5) & 1) << 1) | ((lane >> 3) & 1);
    const int scg = ((lane & 3) ^ gst) * 8;
    const int vrow = lane >> 3;
    const int vcg = ((lane & 7) ^ ((lane >> 3) & 7)) * 8;

    auto stage = [&](int kt, int buf) {
        if (grp == 0) {
#pragma unroll
            for (int i = 0; i < 4; i++)
                gl_lds16(kbase + (size_t)(kt * 64 + wq * 16 + srow) * DHD + i * 32 + scg,
                         &Ks[buf][i * 2048 + wq * 512]);
        } else {
#pragma unroll
            for (int i = 0; i < 4; i++)
                gl_lds16(vtbase + (size_t)(wq * 32 + i * 8 + vrow) * TT + kt * 64 + vcg,
                         &VTs[buf][wq * 2048 + i * 512]);
        }
    };

    stage(0, 0);

    const int gk = (((l15 >> 2) & 1) << 1) | ((l15 >> 1) & 1);

    f32x4 O0[8] = {}, O1[8] = {};
    float m0 = -INFINITY, l0 = 0.f, m1 = -INFINITY, l1 = 0.f;

    union PW { bf16x4 h[2]; bf16x8 v; };

    for (int kt = 0; kt <= ktmax_blk; kt++) {
        int cur = kt & 1;
        __syncthreads();
        if (kt < ktmax_blk) stage(kt + 1, cur ^ 1);

        if (kt > Tq1) continue;
        const bool a0 = (kt <= Tq0);

        f32x4 s0[4], s1[4];
        __builtin_amdgcn_s_setprio(1);
#pragma unroll
        for (int ni = 0; ni < 4; ni++) {
            int rr = (ni >> 1) * 32 + (l15 >> 2) * 8 + (ni & 1) * 4 + (l15 & 3);
            bf16x8 kfl[4];
#pragma unroll
            for (int kc = 0; kc < 4; kc++)
                kfl[kc] = *(const bf16x8*)(&Ks[cur][kc * 2048 + rr * 32 + ((quad ^ gk) * 8)]);
            f32x4 z1 = {};
#pragma unroll
            for (int kc = 0; kc < 4; kc++)
                z1 = __builtin_amdgcn_mfma_f32_16x16x32_bf16(kfl[kc], qf1[kc], z1, 0, 0, 0);
            s1[ni] = z1;
            if (a0) {
                f32x4 z0 = {};
#pragma unroll
                for (int kc = 0; kc < 4; kc++)
                    z0 = __builtin_amdgcn_mfma_f32_16x16x32_bf16(kfl[kc], qf0[kc], z0, 0, 0, 0);
                s0[ni] = z0;
            }
        }
        __builtin_amdgcn_s_setprio(0);

        PW pw0[2], pw1[2];
        {
            if (kt == Tq1) {
#pragma unroll
                for (int ni = 0; ni < 4; ni++)
#pragma unroll
                    for (int r = 0; r < 4; r++)
                        if (dm[ni][r]) s1[ni][r] = -INFINITY;
            }
            float mx = s1[0][0];
#pragma unroll
            for (int ni = 0; ni < 4; ni++)
#pragma unroll
                for (int r = 0; r < 4; r++) mx = fmaxf(mx, s1[ni][r]);
            mx = fmaxf(mx, __shfl_xor(mx, 16));
            mx = fmaxf(mx, __shfl_xor(mx, 32));
            float mold = m1;
            bool noresc = __all(mx <= mold + 8.f);   // T13 defer-max
            float mnew = noresc ? mold : fmaxf(mold, mx);
            float rs = 0.f;
#pragma unroll
            for (int ni = 0; ni < 4; ni++) {
                bf16x4 hv;
#pragma unroll
                for (int r = 0; r < 4; r++) {
                    float pe = __builtin_amdgcn_exp2f(s1[ni][r] - mnew);
                    hv[r] = (bf16)pe;
                    rs += pe;
                }
                pw1[ni >> 1].h[ni & 1] = hv;
            }
            rs += __shfl_xor(rs, 16);
            rs += __shfl_xor(rs, 32);
            if (!noresc) {
                float al = __builtin_amdgcn_exp2f(mold - mnew);
                l1 *= al;
#pragma unroll
                for (int dn = 0; dn < 8; dn++)
#pragma unroll
                    for (int r = 0; r < 4; r++) O1[dn][r] *= al;
                m1 = mnew;
            }
            l1 += rs;
        }
        if (a0) {
            if (kt == Tq0) {
#pragma unroll
                for (int ni = 0; ni < 4; ni++)
#pragma unroll
                    for (int r = 0; r < 4; r++)
                        if (dm[ni][r]) s0[ni][r] = -INFINITY;
            }
            float mx = s0[0][0];
#pragma unroll
            for (int ni = 0; ni < 4; ni++)
#pragma unroll
                for (int r = 0; r < 4; r++) mx = fmaxf(mx, s0[ni][r]);
            mx = fmaxf(mx, __shfl_xor(mx, 16));
            mx = fmaxf(mx, __shfl_xor(mx, 32));
            float mold = m0;
            bool noresc = __all(mx <= mold + 8.f);   // T13 defer-max
            float mnew = noresc ? mold : fmaxf(mold, mx);
            float rs = 0.f;
#pragma unroll
            for (int ni = 0; ni < 4; ni++) {
                bf16x4 hv;
#pragma unroll
                for (int r = 0; r < 4; r++) {
                    float pe = __builtin_amdgcn_exp2f(s0[ni][r] - mnew);
                    hv[r] = (bf16)pe;
                    rs += pe;
                }
                pw0[ni >> 1].h[ni & 1] = hv;
            }
            rs += __shfl_xor(rs, 16);
            rs += __shfl_xor(rs, 32);
            if (!noresc) {
                float al = __builtin_amdgcn_exp2f(mold - mnew);
                l0 *= al;
#pragma unroll
                for (int dn = 0; dn < 8; dn++)
#pragma unroll
                    for (int r = 0; r < 4; r++) O0[dn][r] *= al;
                m0 = mnew;
            }
            l0 += rs;
        }

        __builtin_amdgcn_s_setprio(1);
#pragma unroll
        for (int ni2 = 0; ni2 < 2; ni2++) {
            bf16x8 vfl[8];
#pragma unroll
            for (int dn = 0; dn < 8; dn++)
                vfl[dn] = *(const bf16x8*)(&VTs[cur][(dn * 16 + l15) * 64 +
                                                    (((ni2 * 4 + quad) ^ (l15 & 7)) * 8)]);
#pragma unroll
            for (int dn = 0; dn < 8; dn++)
                O1[dn] = __builtin_amdgcn_mfma_f32_16x16x32_bf16(vfl[dn], pw1[ni2].v, O1[dn], 0, 0, 0);
            if (a0) {
#pragma unroll
                for (int dn = 0; dn < 8; dn++)
                    O0[dn] = __builtin_amdgcn_mfma_f32_16x16x32_bf16(vfl[dn], pw0[ni2].v, O0[dn], 0, 0, 0);
            }
        }
        __builtin_amdgcn_s_setprio(0);
    }

    auto epi = [&](const f32x4* Oc, float lsum, int qt) {
        int qg = qt * 64 + wq * 16 + l15;
        float gi = gates[((size_t)b * TT + qg) * HH + h] / lsum;
#pragma unroll
        for (int dn = 0; dn < 8; dn++) {
            bf16x4 o;
#pragma unroll
            for (int r = 0; r < 4; r++) o[r] = (bf16)(Oc[dn][r] * gi);
            *(bf16x4*)(yb + ((size_t)(b * TT + qg) * HH + h) * DHD + dn * 16 + quad * 4) = o;
        }
    };
    epi(O0, l0, Tq0);
    epi(O1, l1, Tq1);
}

extern "C" void kernel_launch(void* const* d_in, const int* in_sizes, int n_in,
                              void* d_out, int out_size, void* d_ws, size_t ws_size,
                              hipStream_t stream) {
    const float* x    = (const float*)d_in[0];
    const float* cosb = (const float*)d_in[2];
    const float* sinb = (const float*)d_in[3];
    const float* v1   = (const float*)d_in[4];
    const float* Wq   = (const float*)d_in[5];
    const float* Wk   = (const float*)d_in[6];
    const float* Wv   = (const float*)d_in[7];
    const float* Wo   = (const float*)d_in[8];
    const float* gw   = (const float*)d_in[9];
    const float* lam  = (const float*)d_in[10];
    float* out = (float*)d_out;

    char* ws = (char*)d_ws;
    bf16* xb     = (bf16*)(ws);                   // 16,777,216 B (reused later by yb)
    bf16* wqkvb  = (bf16*)(ws + 16777216);        // 12,582,912
    bf16* wob    = (bf16*)(ws + 29360128);        //  8,388,608
    bf16* qb     = (bf16*)(ws + 79691776);        // 16,777,216
    bf16* kb     = (bf16*)(ws + 96468992);        //  4,194,304
    bf16* vtb    = (bf16*)(ws + 100663296);       //  4,194,304
    float* gts   = (float*)(ws + 104857600);      //    262,144
    bf16* yb     = xb;                            // alias: xb dead after QKV GEMM

    // all converts + gates in ONE launch
    cvt_fuse<<<9216, 256, 0, stream>>>(x, Wq, Wk, Wv, Wo, gw, xb, wqkvb, wob, gts);

    // QKV projection + fused rmsnorm/rope/v-mix epilogues
    gemm_bt<1><<<dim3(24, 32), 256, 0, stream>>>(xb, wqkvb, 4096, NQKV, 2048,
                                                 nullptr, qb, kb, vtb, v1,
                                                 cosb, sinb, lam);
    // flash attention -- yb aliases xb; also copies v1 -> out[8388608..]
    fattn<<<256, 512, 0, stream>>>(qb, kb, vtb, gts, yb, v1, out + 8388608);
    // output projection
    gemm_bt<0><<<dim3(16, 32), 256, 0, stream>>>(yb, wob, 4096, 2048, 2048,
                                                 out, nullptr, nullptr, nullptr,
                                                 nullptr, nullptr, nullptr, nullptr);
}

// Round 9
// 287.484 us; speedup vs baseline: 1.1146x; 1.0175x over previous
//
#include <hip/hip_runtime.h>

typedef __bf16 bf16;
typedef __attribute__((ext_vector_type(8))) __bf16 bf16x8;
typedef __attribute__((ext_vector_type(4))) __bf16 bf16x4;
typedef __attribute__((ext_vector_type(4))) float f32x4;
typedef __attribute__((ext_vector_type(4))) short short4v;

// ---- constants for this problem ----
#define BB 2
#define TT 2048
#define DD 2048
#define HH 16
#define HKV 4
#define DHD 128
#define NQKV 3072   // H*DH + 2*HKV*DH

__device__ __forceinline__ void gl_lds16(const bf16* g, bf16* l) {
    __builtin_amdgcn_global_load_lds(
        (const __attribute__((address_space(1))) void*)g,
        (__attribute__((address_space(3))) void*)l, 16, 0, 0);
}

// ---------------- fused fp32->bf16 converts + gates ----------------
// blocks [0,4096):    x -> xb; block == one token row; gates computed inline
// blocks [4096,6144): Wq -> wqkvb
// blocks [6144,6656): Wk -> wqkvb+4194304
// blocks [6656,7168): Wv -> wqkvb+5242880
// blocks [7168,9216): Wo -> wob
__global__ void cvt_fuse(const float* __restrict__ x, const float* __restrict__ Wq,
                         const float* __restrict__ Wk, const float* __restrict__ Wv,
                         const float* __restrict__ Wo, const float* __restrict__ gw,
                         bf16* __restrict__ xb, bf16* __restrict__ wqkvb,
                         bf16* __restrict__ wob, float* __restrict__ gates) {
    const int blk = blockIdx.x, tid = threadIdx.x;
    const float* src; bf16* dst; int i;
    const bool isx = blk < 4096;
    if (isx)              { src = x;  dst = xb;              i = blk * 256 + tid; }
    else if (blk < 6144)  { src = Wq; dst = wqkvb;           i = (blk - 4096) * 256 + tid; }
    else if (blk < 6656)  { src = Wk; dst = wqkvb + 4194304; i = (blk - 6144) * 256 + tid; }
    else if (blk < 7168)  { src = Wv; dst = wqkvb + 5242880; i = (blk - 6656) * 256 + tid; }
    else                  { src = Wo; dst = wob;             i = (blk - 7168) * 256 + tid; }
    float4 a = ((const float4*)src)[i * 2];
    float4 b = ((const float4*)src)[i * 2 + 1];
    bf16x8 v;
    v[0] = (bf16)a.x; v[1] = (bf16)a.y; v[2] = (bf16)a.z; v[3] = (bf16)a.w;
    v[4] = (bf16)b.x; v[5] = (bf16)b.y; v[6] = (bf16)b.z; v[7] = (bf16)b.w;
    *(bf16x8*)(dst + (size_t)i * 8) = v;

    if (isx) {   // block-uniform branch; gates for this token
        __shared__ float xs16[16];
        __shared__ float gws[256];
        gws[tid] = gw[tid];
        if (tid < 2) {
            xs16[tid * 8 + 0] = a.x; xs16[tid * 8 + 1] = a.y;
            xs16[tid * 8 + 2] = a.z; xs16[tid * 8 + 3] = a.w;
            xs16[tid * 8 + 4] = b.x; xs16[tid * 8 + 5] = b.y;
            xs16[tid * 8 + 6] = b.z; xs16[tid * 8 + 7] = b.w;
        }
        __syncthreads();
        if (tid < 16) {
            float z = 0.f;
#pragma unroll
            for (int j = 0; j < 16; j++) z += xs16[j] * gws[tid * 16 + j];
            gates[blk * 16 + tid] = 1.f / (1.f + __expf(-z));
        }
    }
}

// ---------------- GEMM: C = A(MxK) * Bw(NxK)^T, bf16 in, fp32 acc, BK=64 ----------------
// R10 structure (frozen): 256 thr, 128x128 tile, 2 syncthreads/K-tile, multi-
// block/CU TLP + T2 both-sides LDS swizzle + T1 bijective XCD block swizzle.
// MODE 0: plain fp32 store. MODE 1: fused QKV epilogue.
template <int MODE>
__global__ void gemm_bt(const bf16* __restrict__ A, const bf16* __restrict__ Bw,
                        int M, int N, int K,
                        float* __restrict__ Cout,
                        bf16* __restrict__ qb, bf16* __restrict__ kb,
                        bf16* __restrict__ vtb,
                        const float* __restrict__ v1,
                        const float* __restrict__ cosb,
                        const float* __restrict__ sinb,
                        const float* __restrict__ lamp) {
    constexpr int SMEM_ELE = (MODE == 1) ? 17920 : 16384;  // bf16 elements
    __shared__ bf16 smem[SMEM_ELE];
    bf16* As = smem;          // [kc2:2][rc:8][16 rows][32 k] = 8192 ele
    bf16* Bs = smem + 8192;
    const int tid = threadIdx.x;
    const int w = tid >> 6, lane = tid & 63;
    const int l15 = lane & 15, quad = lane >> 4;

    // T1: bijective XCD-aware block swizzle (nwg % 8 == 0 for our grids)
    const int nwg = gridDim.x * gridDim.y;
    int wg = blockIdx.y * gridDim.x + blockIdx.x;
    int swz = (wg & 7) * (nwg >> 3) + (wg >> 3);
    const int bx = swz % gridDim.x, by = swz / gridDim.x;
    const int m0 = by * 128, n0 = bx * 128;
    const int wm = (w & 1) * 64, wn = (w >> 1) * 64;

    f32x4 acc[4][4] = {};
    const int lrow = lane >> 2;                          // 0..15 row within chunk
    const int scol = ((lane & 3) ^ ((lane >> 3) & 3)) * 8;  // T2 source-side swizzle
    const int xs = (quad ^ ((l15 >> 1) & 3)) * 8;           // T2 read-side swizzle

    for (int k0 = 0; k0 < K; k0 += 64) {
#pragma unroll
        for (int i = 0; i < 4; i++) {
            int c = w * 4 + i;           // 0..15
            int kc2 = c >> 3, rc = c & 7;
            int row = rc * 16 + lrow;
            int kk = k0 + kc2 * 32 + scol;
            gl_lds16(A + (size_t)(m0 + row) * K + kk, As + c * 512);
            gl_lds16(Bw + (size_t)(n0 + row) * K + kk, Bs + c * 512);
        }
        __syncthreads();
#pragma unroll
        for (int kc2 = 0; kc2 < 2; kc2++) {
            bf16x8 af[4], bfr[4];
#pragma unroll
            for (int mi = 0; mi < 4; mi++)
                af[mi] = *(const bf16x8*)(As + kc2 * 4096 + ((wm >> 4) + mi) * 512 + l15 * 32 + xs);
#pragma unroll
            for (int ni = 0; ni < 4; ni++)
                bfr[ni] = *(const bf16x8*)(Bs + kc2 * 4096 + ((wn >> 4) + ni) * 512 + l15 * 32 + xs);
#pragma unroll
            for (int mi = 0; mi < 4; mi++)
#pragma unroll
                for (int ni = 0; ni < 4; ni++)
                    acc[mi][ni] = __builtin_amdgcn_mfma_f32_16x16x32_bf16(af[mi], bfr[ni], acc[mi][ni], 0, 0, 0);
        }
        __syncthreads();
    }

    if constexpr (MODE == 0) {
#pragma unroll
        for (int mi = 0; mi < 4; mi++)
#pragma unroll
            for (int ni = 0; ni < 4; ni++)
#pragma unroll
                for (int r = 0; r < 4; r++) {
                    int m = m0 + wm + mi * 16 + quad * 4 + r;
                    int n = n0 + wn + ni * 16 + l15;
                    Cout[(size_t)m * N + n] = acc[mi][ni][r];
                }
    } else {
        const int hid = n0 >> 7;         // 0..23
        const int b = m0 >> 11;
        const int t0 = m0 & (TT - 1);
        bf16* ep = smem;                 // [128 rows][136] transpose buffer

        if (hid < 20) {
            // ---- rmsnorm partials (per row, across the 128-col head) ----
            float* ssum = (float*)(smem + 17408);   // [2][128] fp32
            float ssq[4][4];
#pragma unroll
            for (int mi = 0; mi < 4; mi++)
#pragma unroll
                for (int r = 0; r < 4; r++) {
                    float s = 0.f;
#pragma unroll
                    for (int ni = 0; ni < 4; ni++) {
                        float v = acc[mi][ni][r];
                        s += v * v;
                    }
                    s += __shfl_xor(s, 1);
                    s += __shfl_xor(s, 2);
                    s += __shfl_xor(s, 4);
                    s += __shfl_xor(s, 8);
                    ssq[mi][r] = s;
                }
            if (l15 == 0) {
#pragma unroll
                for (int mi = 0; mi < 4; mi++)
#pragma unroll
                    for (int r = 0; r < 4; r++)
                        ssum[(wn >> 6) * 128 + wm + mi * 16 + quad * 4 + r] = ssq[mi][r];
            }
            __syncthreads();
            const float QSCALE = 0.08838834764831845f * 1.4426950408889634f;
            float rn[4][4];
#pragma unroll
            for (int mi = 0; mi < 4; mi++)
#pragma unroll
                for (int r = 0; r < 4; r++) {
                    int row = wm + mi * 16 + quad * 4 + r;
                    float ss = ssum[row] + ssum[128 + row];
                    float rv = rsqrtf(ss * (1.f / 128.f) + 1e-6f);
                    if (hid < HH) rv *= QSCALE;
                    rn[mi][r] = rv;
                }
            // ---- rope -> ep[t_local][outcol] ----
#pragma unroll
            for (int mi = 0; mi < 4; mi++)
#pragma unroll
                for (int ni = 0; ni < 4; ni++)
#pragma unroll
                    for (int r = 0; r < 4; r++) {
                        float sv = acc[mi][ni][r] * rn[mi][r];
                        float pv = __shfl_xor(sv, 1);
                        int nl = wn + ni * 16 + l15;       // 0..127
                        int j = nl >> 1;                   // 0..63
                        int tl = wm + mi * 16 + quad * 4 + r;
                        float c = cosb[(size_t)(t0 + tl) * 64 + j];
                        float s = sinb[(size_t)(t0 + tl) * 64 + j];
                        float o = (nl & 1) ? (sv * c + pv * s) : (sv * c - pv * s);
                        int oc = (nl & 1) ? (64 + j) : j;
                        ep[tl * 136 + oc] = (bf16)o;
                    }
            __syncthreads();
            bf16* dst = (hid < HH)
                ? (qb + ((size_t)(b * HH + hid) * TT + t0) * DHD)
                : (kb + ((size_t)(b * HKV + (hid - HH)) * TT + t0) * DHD);
            int tl = tid >> 1, half = tid & 1;
#pragma unroll
            for (int c8 = 0; c8 < 8; c8++)
                *(bf16x8*)(dst + (size_t)tl * DHD + half * 64 + c8 * 8) =
                    *(const bf16x8*)(ep + tl * 136 + half * 64 + c8 * 8);
        } else {
            // ---- v: mix with v1, transpose -> vtb (B,HKV,DH,T) ----
            float lam = lamp[0];
            int vh = hid - 20;
            const float* v1b = v1 + ((size_t)(b * HKV + vh) * TT) * DHD;
#pragma unroll
            for (int mi = 0; mi < 4; mi++)
#pragma unroll
            for (int ni = 0; ni < 4; ni++)
#pragma unroll
                for (int r = 0; r < 4; r++) {
                    int d = wn + ni * 16 + l15;
                    int tl = wm + mi * 16 + quad * 4 + r;
                    float val = acc[mi][ni][r];
                    float vm = val + lam * (v1b[(size_t)(t0 + tl) * DHD + d] - val);
                    ep[d * 136 + tl] = (bf16)vm;
                }
            __syncthreads();
            bf16* dstv = vtb + ((size_t)(b * HKV + vh) * DHD) * TT + t0;
            int dd = tid >> 1, half = tid & 1;
#pragma unroll
            for (int c8 = 0; c8 < 8; c8++)
                *(bf16x8*)(dstv + (size_t)dd * TT + half * 64 + c8 * 8) =
                    *(const bf16x8*)(ep + dd * 136 + half * 64 + c8 * 8);
        }
    }
}

// ---------------- flash attention ----------------
// R14 = R12 with the V-stage destination typo FIXED (R8 failed absmax 1.6:
// V dest was transcribed as i*2048+wq*512; the R6-verified V layout
// [128 d][64 k] requires wq*2048+i*512 so that staged d-row
// wq*32+i*8+vrow lands at element (wq*32+i*8+vrow)*64).
// Structure: 512 blocks x 256 thr; each 4-wave block owns Q-tile pair
// {g,31-g} or {15-g,16+g}, stages its own K AND V, iterates to its own
// Tq1 (2 decoupled barrier domains/CU; block-iters -14%).
__global__ __launch_bounds__(256, 2) void fattn(const bf16* __restrict__ qbuf,
                                                const bf16* __restrict__ kbuf,
                                                const bf16* __restrict__ vt,
                                                const float* __restrict__ gates,
                                                bf16* __restrict__ yb,
                                                const float* __restrict__ v1f,
                                                float* __restrict__ vout) {
    __shared__ bf16 Ks[2][8192];      // [kc:4][64 kv][32 d], 16B slot ^ g(row)
    __shared__ bf16 VTs[2][8192];     // [128 d][64 k], slot16 ^= (d&7)

    const int bid = blockIdx.x;          // 512 blocks
    const int bh = bid & 31;             // b*16+h
    const int gg = bid >> 5;             // 0..15
    const int g = gg & 7, qhalf = gg >> 3;
    const int h = bh & 15, b = bh >> 4;
    const int hk = h >> 2;
    const int tid = threadIdx.x, wq = tid >> 6, lane = tid & 63;
    const int l15 = lane & 15, quad = lane >> 4;

    // v1 passthrough: each block copies a disjoint 16 KB chunk
    {
        const float4* s4 = (const float4*)(v1f + (size_t)bid * 4096);
        float4* d4 = (float4*)(vout + (size_t)bid * 4096);
#pragma unroll
        for (int i = 0; i < 4; i++) d4[tid + i * 256] = s4[tid + i * 256];
    }

    const bf16* qbase = qbuf + ((size_t)(b * HH + h) * TT) * DHD;
    const bf16* kbase = kbuf + ((size_t)(b * HKV + hk) * TT) * DHD;
    const bf16* vtbase = vt + ((size_t)(b * HKV + hk) * DHD) * TT;

    const int Tq0 = qhalf ? (15 - g) : g;
    const int Tq1 = qhalf ? (16 + g) : (31 - g);
    const int ktmax_blk = Tq1;

    bf16x8 qf0[4], qf1[4];
#pragma unroll
    for (int kc = 0; kc < 4; kc++) {
        qf0[kc] = *(const bf16x8*)(qbase + (size_t)(Tq0 * 64 + wq * 16 + l15) * DHD + kc * 32 + quad * 8);
        qf1[kc] = *(const bf16x8*)(qbase + (size_t)(Tq1 * 64 + wq * 16 + l15) * DHD + kc * 32 + quad * 8);
    }

    // causal mask with PERMUTED kv positions
    bool dm[4][4];
#pragma unroll
    for (int ni = 0; ni < 4; ni++)
#pragma unroll
        for (int r = 0; r < 4; r++)
            dm[ni][r] = ((ni >> 1) * 32 + quad * 8 + (ni & 1) * 4 + r) > (wq * 16 + l15);

    const int srow = lane >> 2;
    const int gst = (((lane >> 5) & 1) << 1) | ((lane >> 3) & 1);
    const int scg = ((lane & 3) ^ gst) * 8;
    const int vrow = lane >> 3;
    const int vcg = ((lane & 7) ^ ((lane >> 3) & 7)) * 8;

    auto stage = [&](int kt, int buf) {
#pragma unroll
        for (int i = 0; i < 4; i++)
            gl_lds16(kbase + (size_t)(kt * 64 + wq * 16 + srow) * DHD + i * 32 + scg,
                     &Ks[buf][i * 2048 + wq * 512]);
#pragma unroll
        for (int i = 0; i < 4; i++)
            gl_lds16(vtbase + (size_t)(wq * 32 + i * 8 + vrow) * TT + kt * 64 + vcg,
                     &VTs[buf][wq * 2048 + i * 512]);
    };

    stage(0, 0);

    const int gk = (((l15 >> 2) & 1) << 1) | ((l15 >> 1) & 1);

    f32x4 O0[8] = {}, O1[8] = {};
    float m0 = -INFINITY, l0 = 0.f, m1 = -INFINITY, l1 = 0.f;

    union PW { bf16x4 h[2]; bf16x8 v; };

    for (int kt = 0; kt <= ktmax_blk; kt++) {
        int cur = kt & 1;
        __syncthreads();
        if (kt < ktmax_blk) stage(kt + 1, cur ^ 1);

        const bool a0 = (kt <= Tq0);

        f32x4 s0[4], s1[4];
        __builtin_amdgcn_s_setprio(1);
#pragma unroll
        for (int ni = 0; ni < 4; ni++) {
            int rr = (ni >> 1) * 32 + (l15 >> 2) * 8 + (ni & 1) * 4 + (l15 & 3);
            bf16x8 kfl[4];
#pragma unroll
            for (int kc = 0; kc < 4; kc++)
                kfl[kc] = *(const bf16x8*)(&Ks[cur][kc * 2048 + rr * 32 + ((quad ^ gk) * 8)]);
            f32x4 z1 = {};
#pragma unroll
            for (int kc = 0; kc < 4; kc++)
                z1 = __builtin_amdgcn_mfma_f32_16x16x32_bf16(kfl[kc], qf1[kc], z1, 0, 0, 0);
            s1[ni] = z1;
            if (a0) {
                f32x4 z0 = {};
#pragma unroll
                for (int kc = 0; kc < 4; kc++)
                    z0 = __builtin_amdgcn_mfma_f32_16x16x32_bf16(kfl[kc], qf0[kc], z0, 0, 0, 0);
                s0[ni] = z0;
            }
        }
        __builtin_amdgcn_s_setprio(0);

        PW pw0[2], pw1[2];
        {
            if (kt == Tq1) {
#pragma unroll
                for (int ni = 0; ni < 4; ni++)
#pragma unroll
                    for (int r = 0; r < 4; r++)
                        if (dm[ni][r]) s1[ni][r] = -INFINITY;
            }
            float mx = s1[0][0];
#pragma unroll
            for (int ni = 0; ni < 4; ni++)
#pragma unroll
                for (int r = 0; r < 4; r++) mx = fmaxf(mx, s1[ni][r]);
            mx = fmaxf(mx, __shfl_xor(mx, 16));
            mx = fmaxf(mx, __shfl_xor(mx, 32));
            float mold = m1;
            bool noresc = __all(mx <= mold + 8.f);   // T13 defer-max
            float mnew = noresc ? mold : fmaxf(mold, mx);
            float rs = 0.f;
#pragma unroll
            for (int ni = 0; ni < 4; ni++) {
                bf16x4 hv;
#pragma unroll
                for (int r = 0; r < 4; r++) {
                    float pe = __builtin_amdgcn_exp2f(s1[ni][r] - mnew);
                    hv[r] = (bf16)pe;
                    rs += pe;
                }
                pw1[ni >> 1].h[ni & 1] = hv;
            }
            rs += __shfl_xor(rs, 16);
            rs += __shfl_xor(rs, 32);
            if (!noresc) {
                float al = __builtin_amdgcn_exp2f(mold - mnew);
                l1 *= al;
#pragma unroll
                for (int dn = 0; dn < 8; dn++)
#pragma unroll
                    for (int r = 0; r < 4; r++) O1[dn][r] *= al;
                m1 = mnew;
            }
            l1 += rs;
        }
        if (a0) {
            if (kt == Tq0) {
#pragma unroll
                for (int ni = 0; ni < 4; ni++)
#pragma unroll
                    for (int r = 0; r < 4; r++)
                        if (dm[ni][r]) s0[ni][r] = -INFINITY;
            }
            float mx = s0[0][0];
#pragma unroll
            for (int ni = 0; ni < 4; ni++)
#pragma unroll
                for (int r = 0; r < 4; r++) mx = fmaxf(mx, s0[ni][r]);
            mx = fmaxf(mx, __shfl_xor(mx, 16));
            mx = fmaxf(mx, __shfl_xor(mx, 32));
            float mold = m0;
            bool noresc = __all(mx <= mold + 8.f);   // T13 defer-max
            float mnew = noresc ? mold : fmaxf(mold, mx);
            float rs = 0.f;
#pragma unroll
            for (int ni = 0; ni < 4; ni++) {
                bf16x4 hv;
#pragma unroll
                for (int r = 0; r < 4; r++) {
                    float pe = __builtin_amdgcn_exp2f(s0[ni][r] - mnew);
                    hv[r] = (bf16)pe;
                    rs += pe;
                }
                pw0[ni >> 1].h[ni & 1] = hv;
            }
            rs += __shfl_xor(rs, 16);
            rs += __shfl_xor(rs, 32);
            if (!noresc) {
                float al = __builtin_amdgcn_exp2f(mold - mnew);
                l0 *= al;
#pragma unroll
                for (int dn = 0; dn < 8; dn++)
#pragma unroll
                    for (int r = 0; r < 4; r++) O0[dn][r] *= al;
                m0 = mnew;
            }
            l0 += rs;
        }

        __builtin_amdgcn_s_setprio(1);
#pragma unroll
        for (int ni2 = 0; ni2 < 2; ni2++) {
            bf16x8 vfl[8];
#pragma unroll
            for (int dn = 0; dn < 8; dn++)
                vfl[dn] = *(const bf16x8*)(&VTs[cur][(dn * 16 + l15) * 64 +
                                                    (((ni2 * 4 + quad) ^ (l15 & 7)) * 8)]);
#pragma unroll
            for (int dn = 0; dn < 8; dn++)
                O1[dn] = __builtin_amdgcn_mfma_f32_16x16x32_bf16(vfl[dn], pw1[ni2].v, O1[dn], 0, 0, 0);
            if (a0) {
#pragma unroll
                for (int dn = 0; dn < 8; dn++)
                    O0[dn] = __builtin_amdgcn_mfma_f32_16x16x32_bf16(vfl[dn], pw0[ni2].v, O0[dn], 0, 0, 0);
            }
        }
        __builtin_amdgcn_s_setprio(0);
    }

    auto epi = [&](const f32x4* Oc, float lsum, int qt) {
        int qg = qt * 64 + wq * 16 + l15;
        float gi = gates[((size_t)b * TT + qg) * HH + h] / lsum;
#pragma unroll
        for (int dn = 0; dn < 8; dn++) {
            bf16x4 o;
#pragma unroll
            for (int r = 0; r < 4; r++) o[r] = (bf16)(Oc[dn][r] * gi);
            *(bf16x4*)(yb + ((size_t)(b * TT + qg) * HH + h) * DHD + dn * 16 + quad * 4) = o;
        }
    };
    epi(O0, l0, Tq0);
    epi(O1, l1, Tq1);
}

extern "C" void kernel_launch(void* const* d_in, const int* in_sizes, int n_in,
                              void* d_out, int out_size, void* d_ws, size_t ws_size,
                              hipStream_t stream) {
    const float* x    = (const float*)d_in[0];
    const float* cosb = (const float*)d_in[2];
    const float* sinb = (const float*)d_in[3];
    const float* v1   = (const float*)d_in[4];
    const float* Wq   = (const float*)d_in[5];
    const float* Wk   = (const float*)d_in[6];
    const float* Wv   = (const float*)d_in[7];
    const float* Wo   = (const float*)d_in[8];
    const float* gw   = (const float*)d_in[9];
    const float* lam  = (const float*)d_in[10];
    float* out = (float*)d_out;

    char* ws = (char*)d_ws;
    bf16* xb     = (bf16*)(ws);                   // 16,777,216 B (reused later by yb)
    bf16* wqkvb  = (bf16*)(ws + 16777216);        // 12,582,912
    bf16* wob    = (bf16*)(ws + 29360128);        //  8,388,608
    bf16* qb     = (bf16*)(ws + 79691776);        // 16,777,216
    bf16* kb     = (bf16*)(ws + 96468992);        //  4,194,304
    bf16* vtb    = (bf16*)(ws + 100663296);       //  4,194,304
    float* gts   = (float*)(ws + 104857600);      //    262,144
    bf16* yb     = xb;                            // alias: xb dead after QKV GEMM

    // all converts + gates in ONE launch
    cvt_fuse<<<9216, 256, 0, stream>>>(x, Wq, Wk, Wv, Wo, gw, xb, wqkvb, wob, gts);

    // QKV projection + fused rmsnorm/rope/v-mix epilogues
    gemm_bt<1><<<dim3(24, 32), 256, 0, stream>>>(xb, wqkvb, 4096, NQKV, 2048,
                                                 nullptr, qb, kb, vtb, v1,
                                                 cosb, sinb, lam);
    // flash attention -- yb aliases xb; also copies v1 -> out[8388608..]
    fattn<<<512, 256, 0, stream>>>(qb, kb, vtb, gts, yb, v1, out + 8388608);
    // output projection
    gemm_bt<0><<<dim3(16, 32), 256, 0, stream>>>(yb, wob, 4096, 2048, 2048,
                                                 out, nullptr, nullptr, nullptr,
                                                 nullptr, nullptr, nullptr, nullptr);
}